// Round 3
// baseline (778.490 us; speedup 1.0000x reference)
//
#include <hip/hip_runtime.h>
#include <stdint.h>
#include <math.h>

// Problem constants (B=2,S=2048 -> T=4096 tokens), D=1024, U=4096, E=8, K=2
#define TTOK 4096
#define DDIM 1024
#define UDIM 4096
#define NEXP 8
#define KSPLIT 4            // split-K chunks for stage_down (K=4096 -> 4x1024)
#define NPAIR (TTOK * 2)    // 8192 (token,expert) pairs
#define EPAD 72             // epilogue LDS tile row stride (shorts); 144B = 16B-mult, 4-way banks

using float4v  = __attribute__((ext_vector_type(4))) float;
using short8   = __attribute__((ext_vector_type(8))) short;
using ushort8  = __attribute__((ext_vector_type(8))) unsigned short;

__device__ __forceinline__ unsigned short f2bf(float f) {
  union { float f; unsigned u; } v; v.f = f;
  unsigned r = v.u + 0x7FFFu + ((v.u >> 16) & 1u);  // RNE
  return (unsigned short)(r >> 16);
}
__device__ __forceinline__ float bf2f(unsigned short u) {
  union { unsigned u; float f; } v; v.u = ((unsigned)u) << 16;
  return v.f;
}
__device__ __forceinline__ void load_lds16(const void* g, void* l) {
  __builtin_amdgcn_global_load_lds(
      (const __attribute__((address_space(1))) unsigned int*)g,
      (__attribute__((address_space(3))) unsigned int*)l, 16, 0, 0);
}
__device__ __forceinline__ ushort8 pack8(float4v a, float4v b) {
  ushort8 o;
  o[0]=f2bf(a[0]); o[1]=f2bf(a[1]); o[2]=f2bf(a[2]); o[3]=f2bf(a[3]);
  o[4]=f2bf(b[0]); o[5]=f2bf(b[1]); o[6]=f2bf(b[2]); o[7]=f2bf(b[3]);
  return o;
}

// ---------------- router: logits, top-2, softmax, expert lists ----------------
__global__ void router_kernel(const float* __restrict__ x,
                              const float* __restrict__ wr,
                              int* __restrict__ counts, int* __restrict__ list,
                              float* __restrict__ wpair, int* __restrict__ epair) {
  const int t = blockIdx.x * 4 + (threadIdx.x >> 6);
  const int lane = threadIdx.x & 63;
  float acc[NEXP];
#pragma unroll
  for (int e = 0; e < NEXP; e++) acc[e] = 0.0f;
  const float* xr = x + (size_t)t * DDIM;
  for (int d = lane; d < DDIM; d += 64) {
    float xv = xr[d];
#pragma unroll
    for (int e = 0; e < NEXP; e++) acc[e] += xv * wr[e * DDIM + d];
  }
#pragma unroll
  for (int e = 0; e < NEXP; e++) {
#pragma unroll
    for (int off = 32; off > 0; off >>= 1) acc[e] += __shfl_xor(acc[e], off, 64);
  }
  if (lane == 0) {
    int e0 = 0; float l0 = acc[0];
    for (int e = 1; e < NEXP; e++) if (acc[e] > l0) { l0 = acc[e]; e0 = e; }
    int e1 = -1; float l1 = -3.4e38f;
    for (int e = 0; e < NEXP; e++) if (e != e0 && acc[e] > l1) { l1 = acc[e]; e1 = e; }
    float s1 = expf(l1 - l0);             // l0 >= l1
    float inv = 1.0f / (1.0f + s1);
    int p0 = atomicAdd(&counts[e0], 1);
    list[e0 * TTOK + p0] = 2 * t;
    wpair[2 * t] = inv;  epair[2 * t] = e0;
    int p1 = atomicAdd(&counts[e1], 1);
    list[e1 * TTOK + p1] = 2 * t + 1;
    wpair[2 * t + 1] = s1 * inv;  epair[2 * t + 1] = e1;
  }
}

// ---------------- stage A: h[pair,u] = gelu(x . Wup + bup), fp32 in, bf16 staging ----------------
// grid (UDIM/128, 32, NEXP), block 256. 128x128x32 tile; epilogue LDS-bounce coalesced store.
__global__ __launch_bounds__(256, 2) void stage_up_k(
    const float* __restrict__ x, const float* __restrict__ wu,
    const float* __restrict__ bup, const int* __restrict__ counts,
    const int* __restrict__ list, unsigned short* __restrict__ h) {
  const int e = blockIdx.z, mt = blockIdx.y, nt = blockIdx.x;
  const int cnt = counts[e];
  if (mt * 128 >= cnt) return;
  const int rem = min(128, cnt - mt * 128);
  const int* lst = list + e * TTOK + mt * 128;

  __shared__ __align__(16) unsigned short S[128 * EPAD];  // 18432 B; staging uses first 8192
  unsigned short* As = S;
  unsigned short* Bs = S + 4096;

  const int tid = threadIdx.x;
  const int wave = tid >> 6, lane = tid & 63;
  const int srow = tid >> 2, cell = tid & 3;

  const int tok0 = lst[min(srow, rem - 1)] >> 1;
  const int tok1 = lst[min(srow + 64, rem - 1)] >> 1;
  const float* xa0 = x + (size_t)tok0 * DDIM;
  const float* xa1 = x + (size_t)tok1 * DDIM;
  const float* wb0 = wu + ((size_t)e * UDIM + nt * 128 + srow) * DDIM;
  const float* wb1 = wb0 + (size_t)64 * DDIM;

  const int lds = srow * 32 + cell * 8;  // shorts: row stride 32, 8 shorts/cell
  const int ldd = lds + 64 * 32;

  const int wm = wave >> 1, wn = wave & 1;
  const int lane15 = lane & 15, quad = lane >> 4;
  const int aoff = (wm * 64 + lane15) * 32 + quad * 8;
  const int boff = (wn * 64 + lane15) * 32 + quad * 8;

  float4v acc[4][4];
#pragma unroll
  for (int i = 0; i < 4; i++)
#pragma unroll
    for (int j = 0; j < 4; j++) acc[i][j] = (float4v){0.f, 0.f, 0.f, 0.f};

  for (int k0 = 0; k0 < DDIM; k0 += 32) {
    const int kf = k0 + cell * 8;
    float4v a0 = *(const float4v*)(xa0 + kf), a1 = *(const float4v*)(xa0 + kf + 4);
    float4v a2 = *(const float4v*)(xa1 + kf), a3 = *(const float4v*)(xa1 + kf + 4);
    float4v b0 = *(const float4v*)(wb0 + kf), b1 = *(const float4v*)(wb0 + kf + 4);
    float4v b2 = *(const float4v*)(wb1 + kf), b3 = *(const float4v*)(wb1 + kf + 4);
    *(ushort8*)(As + lds) = pack8(a0, a1);
    *(ushort8*)(As + ldd) = pack8(a2, a3);
    *(ushort8*)(Bs + lds) = pack8(b0, b1);
    *(ushort8*)(Bs + ldd) = pack8(b2, b3);
    __syncthreads();
    short8 af[4], bfr[4];
#pragma unroll
    for (int mi = 0; mi < 4; mi++) af[mi] = *(const short8*)(As + aoff + mi * 512);
#pragma unroll
    for (int ni = 0; ni < 4; ni++) bfr[ni] = *(const short8*)(Bs + boff + ni * 512);
#pragma unroll
    for (int mi = 0; mi < 4; mi++)
#pragma unroll
      for (int ni = 0; ni < 4; ni++)
        acc[mi][ni] = __builtin_amdgcn_mfma_f32_16x16x32_bf16(af[mi], bfr[ni], acc[mi][ni], 0, 0, 0);
    __syncthreads();
  }

  // epilogue: +bias, exact gelu -> bf16, LDS bounce, coalesced 16B stores
  const int ucol0 = nt * 128 + wn * 64;
  float bias[4];
#pragma unroll
  for (int ni = 0; ni < 4; ni++) bias[ni] = bup[e * UDIM + ucol0 + ni * 16 + lane15];
  const int row = tid >> 1, seg = tid & 1;
  const int opair = (row < rem) ? lst[row] : -1;
#pragma unroll
  for (int hh = 0; hh < 2; hh++) {
    if (wn == hh) {
#pragma unroll
      for (int mi = 0; mi < 4; mi++)
#pragma unroll
        for (int r = 0; r < 4; r++) {
          const int rl = wm * 64 + mi * 16 + quad * 4 + r;
#pragma unroll
          for (int ni = 0; ni < 4; ni++) {
            float v = acc[mi][ni][r] + bias[ni];
            v = 0.5f * v * (1.0f + erff(v * 0.70710678118654752f));
            S[rl * EPAD + ni * 16 + lane15] = f2bf(v);
          }
        }
    }
    __syncthreads();
    if (opair >= 0) {
      unsigned short* dst = h + (size_t)opair * UDIM + nt * 128 + hh * 64 + seg * 32;
      const unsigned short* src = S + row * EPAD + seg * 32;
#pragma unroll
      for (int c = 0; c < 4; c++) *(ushort8*)(dst + c * 8) = *(const ushort8*)(src + c * 8);
    }
    __syncthreads();
  }
}

// ---------------- stage B: partials (or atomics) of h . Wdown ----------------
// grid (DDIM/128, 32*KSPLIT, NEXP), block 256. PARTM: bf16 partials, coalesced.
template <bool PARTM>
__global__ __launch_bounds__(256, 2) void stage_down_k(
    const unsigned short* __restrict__ h, const float* __restrict__ wd,
    const float* __restrict__ bdn, const float* __restrict__ wpair,
    const int* __restrict__ counts, const int* __restrict__ list,
    unsigned short* __restrict__ part, float* __restrict__ out) {
  const int e = blockIdx.z, mt = blockIdx.y >> 2, kc = blockIdx.y & 3, nt = blockIdx.x;
  const int cnt = counts[e];
  if (mt * 128 >= cnt) return;
  const int rem = min(128, cnt - mt * 128);
  const int* lst = list + e * TTOK + mt * 128;

  __shared__ __align__(16) unsigned short S[128 * EPAD];
  unsigned short* As = S;
  unsigned short* Bs = S + 4096;

  const int tid = threadIdx.x;
  const int wave = tid >> 6, lane = tid & 63;
  const int srow = tid >> 2, cell = tid & 3;

  const int p0 = lst[min(srow, rem - 1)];
  const int p1 = lst[min(srow + 64, rem - 1)];
  constexpr int KCH = UDIM / KSPLIT;  // 1024
  const char* ha0 = (const char*)h + ((size_t)p0 * UDIM + kc * KCH) * 2;
  const char* ha1 = (const char*)h + ((size_t)p1 * UDIM + kc * KCH) * 2;
  const float* wb0 = wd + ((size_t)e * DDIM + nt * 128 + srow) * UDIM + kc * KCH;
  const float* wb1 = wb0 + (size_t)64 * UDIM;

  const int lds = srow * 32 + cell * 8;     // shorts
  const int ldd = lds + 64 * 32;
  const int ldb0 = srow * 64 + cell * 16;   // bytes, for global_load_lds of A
  const int ldb1 = ldb0 + 64 * 64;

  const int wm = wave >> 1, wn = wave & 1;
  const int lane15 = lane & 15, quad = lane >> 4;
  const int aoff = (wm * 64 + lane15) * 32 + quad * 8;
  const int boff = (wn * 64 + lane15) * 32 + quad * 8;

  float4v acc[4][4];
#pragma unroll
  for (int i = 0; i < 4; i++)
#pragma unroll
    for (int j = 0; j < 4; j++) acc[i][j] = (float4v){0.f, 0.f, 0.f, 0.f};

  for (int k0 = 0; k0 < KCH; k0 += 32) {
    const int kb = k0 * 2 + cell * 16;
    load_lds16(ha0 + kb, (char*)As + ldb0);
    load_lds16(ha1 + kb, (char*)As + ldb1);
    const int kf = k0 + cell * 8;
    float4v b0 = *(const float4v*)(wb0 + kf), b1 = *(const float4v*)(wb0 + kf + 4);
    float4v b2 = *(const float4v*)(wb1 + kf), b3 = *(const float4v*)(wb1 + kf + 4);
    *(ushort8*)(Bs + lds) = pack8(b0, b1);
    *(ushort8*)(Bs + ldd) = pack8(b2, b3);
    __syncthreads();
    short8 af[4], bfr[4];
#pragma unroll
    for (int mi = 0; mi < 4; mi++) af[mi] = *(const short8*)(As + aoff + mi * 512);
#pragma unroll
    for (int ni = 0; ni < 4; ni++) bfr[ni] = *(const short8*)(Bs + boff + ni * 512);
#pragma unroll
    for (int mi = 0; mi < 4; mi++)
#pragma unroll
      for (int ni = 0; ni < 4; ni++)
        acc[mi][ni] = __builtin_amdgcn_mfma_f32_16x16x32_bf16(af[mi], bfr[ni], acc[mi][ni], 0, 0, 0);
    __syncthreads();
  }

  const int dcol0 = nt * 128 + wn * 64;
  if constexpr (PARTM) {
    // pure partial -> bf16 -> LDS bounce -> coalesced store to part[kc][pair][*]
    const int row = tid >> 1, seg = tid & 1;
    const int opair = (row < rem) ? lst[row] : -1;
#pragma unroll
    for (int hh = 0; hh < 2; hh++) {
      if (wn == hh) {
#pragma unroll
        for (int mi = 0; mi < 4; mi++)
#pragma unroll
          for (int r = 0; r < 4; r++) {
            const int rl = wm * 64 + mi * 16 + quad * 4 + r;
#pragma unroll
            for (int ni = 0; ni < 4; ni++)
              S[rl * EPAD + ni * 16 + lane15] = f2bf(acc[mi][ni][r]);
          }
      }
      __syncthreads();
      if (opair >= 0) {
        unsigned short* dst = part + ((size_t)kc * NPAIR + opair) * DDIM + nt * 128 + hh * 64 + seg * 32;
        const unsigned short* src = S + row * EPAD + seg * 32;
#pragma unroll
        for (int c = 0; c < 4; c++) *(ushort8*)(dst + c * 8) = *(const ushort8*)(src + c * 8);
      }
      __syncthreads();
    }
  } else {
    float bias[4];
#pragma unroll
    for (int ni = 0; ni < 4; ni++)
      bias[ni] = (kc == 0) ? bdn[e * DDIM + dcol0 + ni * 16 + lane15] : 0.0f;
#pragma unroll
    for (int mi = 0; mi < 4; mi++)
#pragma unroll
      for (int r = 0; r < 4; r++) {
        const int mrow = wm * 64 + mi * 16 + quad * 4 + r;
        if (mrow < rem) {
          const int pair = lst[mrow];
          const float w = wpair[pair];
          float* orow = out + (size_t)(pair >> 1) * DDIM;
#pragma unroll
          for (int ni = 0; ni < 4; ni++)
            atomicAdd(&orow[dcol0 + ni * 16 + lane15], w * (acc[mi][ni][r] + bias[ni]));
        }
      }
  }
}

// ---------------- combine: out[t,d] = sum_j w_j * (bdn[e_j,d] + sum_kc part[kc,2t+j,d]) ----------------
__global__ void combine_kernel(const unsigned short* __restrict__ part,
                               const float* __restrict__ bdn,
                               const float* __restrict__ wpair,
                               const int* __restrict__ epair,
                               float* __restrict__ out) {
  const int idx = blockIdx.x * 256 + threadIdx.x;   // 524288 total
  const int t = idx >> 7, c8 = (idx & 127) * 8;
  const size_t kstride = (size_t)NPAIR * DDIM;
  const unsigned short* pa = part + (size_t)(2 * t) * DDIM + c8;
  float s0[8], s1[8];
#pragma unroll
  for (int j = 0; j < 8; j++) { s0[j] = 0.f; s1[j] = 0.f; }
#pragma unroll
  for (int kc = 0; kc < KSPLIT; kc++) {
    ushort8 a = *(const ushort8*)(pa + kc * kstride);
    ushort8 b = *(const ushort8*)(pa + kc * kstride + DDIM);
#pragma unroll
    for (int j = 0; j < 8; j++) { s0[j] += bf2f(a[j]); s1[j] += bf2f(b[j]); }
  }
  const float w0 = wpair[2 * t], w1 = wpair[2 * t + 1];
  const int e0 = epair[2 * t], e1 = epair[2 * t + 1];
  const float* b0 = bdn + e0 * DDIM + c8;
  const float* b1 = bdn + e1 * DDIM + c8;
  float4v o[2];
#pragma unroll
  for (int half = 0; half < 2; half++)
#pragma unroll
    for (int j = 0; j < 4; j++) {
      const int jj = half * 4 + j;
      o[half][j] = w0 * (s0[jj] + b0[jj]) + w1 * (s1[jj] + b1[jj]);
    }
  float4v* dst = (float4v*)(out + (size_t)t * DDIM + c8);
  dst[0] = o[0]; dst[1] = o[1];
}

extern "C" void kernel_launch(void* const* d_in, const int* in_sizes, int n_in,
                              void* d_out, int out_size, void* d_ws, size_t ws_size,
                              hipStream_t stream) {
  (void)in_sizes; (void)n_in; (void)out_size;
  const float* x        = (const float*)d_in[0];
  const float* w_router = (const float*)d_in[1];
  const float* w_up     = (const float*)d_in[2];
  const float* b_up     = (const float*)d_in[3];
  const float* w_down   = (const float*)d_in[4];
  const float* b_down   = (const float*)d_in[5];
  float* out = (float*)d_out;

  char* ws = (char*)d_ws;
  size_t off = 0;
  auto take = [&](size_t b) { size_t o = off; off = (off + b + 255) & ~(size_t)255; return o; };
  unsigned short* h = (unsigned short*)(ws + take((size_t)NPAIR * UDIM * 2));   // 64 MiB
  int* counts       = (int*)(ws + take(NEXP * 4));
  int* list         = (int*)(ws + take((size_t)NEXP * TTOK * 4));
  float* wpair      = (float*)(ws + take((size_t)NPAIR * 4));
  int* epair        = (int*)(ws + take((size_t)NPAIR * 4));
  size_t part_off   = take((size_t)KSPLIT * NPAIR * DDIM * 2);                  // 64 MiB
  const bool partmode = ws_size >= off;

  hipMemsetAsync(counts, 0, NEXP * 4, stream);
  router_kernel<<<TTOK / 4, 256, 0, stream>>>(x, w_router, counts, list, wpair, epair);
  stage_up_k<<<dim3(UDIM / 128, 32, NEXP), 256, 0, stream>>>(x, w_up, b_up, counts, list, h);

  if (partmode) {
    unsigned short* part = (unsigned short*)(ws + part_off);
    stage_down_k<true><<<dim3(DDIM / 128, 32 * KSPLIT, NEXP), 256, 0, stream>>>(
        h, w_down, b_down, wpair, counts, list, part, out);
    combine_kernel<<<TTOK * DDIM / 8 / 256, 256, 0, stream>>>(part, b_down, wpair, epair, out);
  } else {
    hipMemsetAsync(out, 0, (size_t)TTOK * DDIM * 4, stream);
    stage_down_k<false><<<dim3(DDIM / 128, 32 * KSPLIT, NEXP), 256, 0, stream>>>(
        h, w_down, b_down, wpair, counts, list, (unsigned short*)nullptr, out);
  }
}

// Round 4
// 723.886 us; speedup vs baseline: 1.0754x; 1.0754x over previous
//
#include <hip/hip_runtime.h>
#include <stdint.h>
#include <math.h>

// Problem constants (B=2,S=2048 -> T=4096 tokens), D=1024, U=4096, E=8, K=2
#define TTOK 4096
#define DDIM 1024
#define UDIM 4096
#define NEXP 8
#define KSPLIT 4            // split-K chunks for stage_down (K=4096 -> 4x1024)
#define NPAIR (TTOK * 2)
#define EPAD 72             // epilogue LDS bounce row stride (shorts)

using float4v  = __attribute__((ext_vector_type(4))) float;
using short8   = __attribute__((ext_vector_type(8))) short;
using ushort4v = __attribute__((ext_vector_type(4))) unsigned short;
using ushort8  = __attribute__((ext_vector_type(8))) unsigned short;

__device__ __forceinline__ unsigned short f2bf(float f) {
  union { float f; unsigned u; } v; v.f = f;
  unsigned r = v.u + 0x7FFFu + ((v.u >> 16) & 1u);  // RNE
  return (unsigned short)(r >> 16);
}
__device__ __forceinline__ void load_lds16(const void* g, void* l) {
  __builtin_amdgcn_global_load_lds(
      (const __attribute__((address_space(1))) unsigned int*)g,
      (__attribute__((address_space(3))) unsigned int*)l, 16, 0, 0);
}
__device__ __forceinline__ ushort8 pack8(float4v a, float4v b) {
  ushort8 o;
  o[0]=f2bf(a[0]); o[1]=f2bf(a[1]); o[2]=f2bf(a[2]); o[3]=f2bf(a[3]);
  o[4]=f2bf(b[0]); o[5]=f2bf(b[1]); o[6]=f2bf(b[2]); o[7]=f2bf(b[3]);
  return o;
}

// ---------------- prep: zero counts + out, cvt x / w_up / w_down to bf16 ----------------
__global__ void prep_kernel(const float4v* __restrict__ x,
                            const float4v* __restrict__ wu,
                            const float4v* __restrict__ wd,
                            ushort4v* __restrict__ xb,
                            ushort4v* __restrict__ wub,
                            ushort4v* __restrict__ wdb,
                            float4v* __restrict__ out,
                            int* __restrict__ counts) {
  const int tid = blockIdx.x * blockDim.x + threadIdx.x;
  const int stride = gridDim.x * blockDim.x;
  if (tid < NEXP) counts[tid] = 0;
  const int W4 = NEXP * UDIM * DDIM / 4;
  for (int i = tid; i < W4; i += stride) {
    float4v a = wu[i], b = wd[i];
    ushort4v oa, ob;
    oa[0]=f2bf(a[0]); oa[1]=f2bf(a[1]); oa[2]=f2bf(a[2]); oa[3]=f2bf(a[3]);
    ob[0]=f2bf(b[0]); ob[1]=f2bf(b[1]); ob[2]=f2bf(b[2]); ob[3]=f2bf(b[3]);
    wub[i] = oa; wdb[i] = ob;
  }
  const int X4 = TTOK * DDIM / 4;
  for (int i = tid; i < X4; i += stride) {
    float4v a = x[i];
    ushort4v oa;
    oa[0]=f2bf(a[0]); oa[1]=f2bf(a[1]); oa[2]=f2bf(a[2]); oa[3]=f2bf(a[3]);
    xb[i] = oa;
    out[i] = (float4v){0.f, 0.f, 0.f, 0.f};
  }
}

__global__ void zero_out_counts(float4v* __restrict__ out, int* __restrict__ counts) {
  const int tid = blockIdx.x * blockDim.x + threadIdx.x;
  if (tid < NEXP) counts[tid] = 0;
  const int O4 = TTOK * DDIM / 4;
  const int stride = gridDim.x * blockDim.x;
  for (int i = tid; i < O4; i += stride) out[i] = (float4v){0.f, 0.f, 0.f, 0.f};
}

// ---------------- router ----------------
__global__ void router_kernel(const float* __restrict__ x,
                              const float* __restrict__ wr,
                              int* __restrict__ counts, int* __restrict__ list,
                              float* __restrict__ wpair) {
  const int t = blockIdx.x * 4 + (threadIdx.x >> 6);
  const int lane = threadIdx.x & 63;
  float acc[NEXP];
#pragma unroll
  for (int e = 0; e < NEXP; e++) acc[e] = 0.0f;
  const float* xr = x + (size_t)t * DDIM;
  for (int d = lane; d < DDIM; d += 64) {
    float xv = xr[d];
#pragma unroll
    for (int e = 0; e < NEXP; e++) acc[e] += xv * wr[e * DDIM + d];
  }
#pragma unroll
  for (int e = 0; e < NEXP; e++) {
#pragma unroll
    for (int off = 32; off > 0; off >>= 1) acc[e] += __shfl_xor(acc[e], off, 64);
  }
  if (lane == 0) {
    int e0 = 0; float l0 = acc[0];
    for (int e = 1; e < NEXP; e++) if (acc[e] > l0) { l0 = acc[e]; e0 = e; }
    int e1 = -1; float l1 = -3.4e38f;
    for (int e = 0; e < NEXP; e++) if (e != e0 && acc[e] > l1) { l1 = acc[e]; e1 = e; }
    float s1 = expf(l1 - l0);
    float inv = 1.0f / (1.0f + s1);
    int p0 = atomicAdd(&counts[e0], 1);
    list[e0 * TTOK + p0] = 2 * t;
    wpair[2 * t] = inv;
    int p1 = atomicAdd(&counts[e1], 1);
    list[e1 * TTOK + p1] = 2 * t + 1;
    wpair[2 * t + 1] = s1 * inv;
  }
}

// ======== stage A: h[pair,u] = gelu(x . Wup + bup).  BK=64 (2x32 subtiles) ========
// grid (UDIM/128, 32, NEXP), block 256, 4 blocks/CU target.
template <bool SRCBF>
__global__ __launch_bounds__(256, 4) void stage_up_k(
    const void* __restrict__ xsrc, const void* __restrict__ wsrc,
    const float* __restrict__ bup, const int* __restrict__ counts,
    const int* __restrict__ list, unsigned short* __restrict__ h) {
  const int e = blockIdx.z, mt = blockIdx.y, nt = blockIdx.x;
  const int cnt = counts[e];
  if (mt * 128 >= cnt) return;
  const int rem = min(128, cnt - mt * 128);
  const int* lst = list + e * TTOK + mt * 128;

  // staging: per matrix 2 subtiles x (128 rows x 32 cols bf16) = 16 KiB; total 32 KiB
  __shared__ __align__(16) unsigned short S[16384];
  unsigned short* As = S;          // [2][64*64] shorts? layout: s*4096 + row*32 + col8*8
  unsigned short* Bs = S + 8192;

  const int tid = threadIdx.x;
  const int wave = tid >> 6, lane = tid & 63;
  const int srow = tid >> 2, cell = tid & 3;

  const int tok0 = lst[min(srow, rem - 1)] >> 1;
  const int tok1 = lst[min(srow + 64, rem - 1)] >> 1;
  constexpr int ELT = SRCBF ? 2 : 4;
  const char* xa0 = (const char*)xsrc + (size_t)tok0 * DDIM * ELT;
  const char* xa1 = (const char*)xsrc + (size_t)tok1 * DDIM * ELT;
  const char* wb0 = (const char*)wsrc + ((size_t)e * UDIM + nt * 128 + srow) * DDIM * ELT;
  const char* wb1 = wb0 + (size_t)64 * DDIM * ELT;

  // LDS byte dest (wave-uniform + lane*16): s*8192 + tid*16 (+4096 for row+64)
  const int ld0 = tid * 16;

  const int wm = wave >> 1, wn = wave & 1;
  const int lane15 = lane & 15, quad = lane >> 4;
  const int aoff = (wm * 64 + lane15) * 32 + quad * 8;
  const int boff = (wn * 64 + lane15) * 32 + quad * 8;

  float4v acc[4][4];
#pragma unroll
  for (int i = 0; i < 4; i++)
#pragma unroll
    for (int j = 0; j < 4; j++) acc[i][j] = (float4v){0.f, 0.f, 0.f, 0.f};

  for (int k0 = 0; k0 < DDIM; k0 += 64) {
#pragma unroll
    for (int s = 0; s < 2; s++) {
      if constexpr (SRCBF) {
        const int kb = (k0 + s * 32) * 2 + cell * 16;
        load_lds16(xa0 + kb, (char*)As + s * 8192 + ld0);
        load_lds16(xa1 + kb, (char*)As + s * 8192 + 4096 + ld0);
        load_lds16(wb0 + kb, (char*)Bs + s * 8192 + ld0);
        load_lds16(wb1 + kb, (char*)Bs + s * 8192 + 4096 + ld0);
      } else {
        const int kb = (k0 + s * 32) * 4 + cell * 32;
        float4v a0 = *(const float4v*)(xa0 + kb), a1 = *(const float4v*)(xa0 + kb + 16);
        float4v a2 = *(const float4v*)(xa1 + kb), a3 = *(const float4v*)(xa1 + kb + 16);
        float4v b0 = *(const float4v*)(wb0 + kb), b1 = *(const float4v*)(wb0 + kb + 16);
        float4v b2 = *(const float4v*)(wb1 + kb), b3 = *(const float4v*)(wb1 + kb + 16);
        *(ushort8*)((char*)As + s * 8192 + ld0) = pack8(a0, a1);
        *(ushort8*)((char*)As + s * 8192 + 4096 + ld0) = pack8(a2, a3);
        *(ushort8*)((char*)Bs + s * 8192 + ld0) = pack8(b0, b1);
        *(ushort8*)((char*)Bs + s * 8192 + 4096 + ld0) = pack8(b2, b3);
      }
    }
    __syncthreads();
#pragma unroll
    for (int s = 0; s < 2; s++) {
      short8 af[4], bfr[4];
#pragma unroll
      for (int mi = 0; mi < 4; mi++) af[mi] = *(const short8*)(As + s * 4096 + aoff + mi * 512);
#pragma unroll
      for (int ni = 0; ni < 4; ni++) bfr[ni] = *(const short8*)(Bs + s * 4096 + boff + ni * 512);
#pragma unroll
      for (int mi = 0; mi < 4; mi++)
#pragma unroll
        for (int ni = 0; ni < 4; ni++)
          acc[mi][ni] = __builtin_amdgcn_mfma_f32_16x16x32_bf16(af[mi], bfr[ni], acc[mi][ni], 0, 0, 0);
    }
    __syncthreads();
  }

  // epilogue: +bias, exact gelu -> bf16, LDS bounce, coalesced 16B stores
  const int ucol0 = nt * 128 + wn * 64;
  float bias[4];
#pragma unroll
  for (int ni = 0; ni < 4; ni++) bias[ni] = bup[e * UDIM + ucol0 + ni * 16 + lane15];
  const int row = tid >> 1, seg = tid & 1;
  const int opair = (row < rem) ? lst[row] : -1;
#pragma unroll
  for (int hh = 0; hh < 2; hh++) {
    if (wn == hh) {
#pragma unroll
      for (int mi = 0; mi < 4; mi++)
#pragma unroll
        for (int r = 0; r < 4; r++) {
          const int rl = wm * 64 + mi * 16 + quad * 4 + r;
#pragma unroll
          for (int ni = 0; ni < 4; ni++) {
            float v = acc[mi][ni][r] + bias[ni];
            v = 0.5f * v * (1.0f + erff(v * 0.70710678118654752f));
            S[rl * EPAD + ni * 16 + lane15] = f2bf(v);
          }
        }
    }
    __syncthreads();
    if (opair >= 0) {
      unsigned short* dst = h + (size_t)opair * UDIM + nt * 128 + hh * 64 + seg * 32;
      const unsigned short* src = S + row * EPAD + seg * 32;
#pragma unroll
      for (int c = 0; c < 4; c++) *(ushort8*)(dst + c * 8) = *(const ushort8*)(src + c * 8);
    }
    __syncthreads();
  }
}

// ======== stage B: out[tok] += w * (h . Wdown + bdn). BK=64, split-K x4, atomics ========
// grid (DDIM/128, 32*KSPLIT, NEXP), block 256.
template <bool WBF>
__global__ __launch_bounds__(256, 4) void stage_down_k(
    const unsigned short* __restrict__ h, const void* __restrict__ wsrc,
    const float* __restrict__ bdn, const float* __restrict__ wpair,
    const int* __restrict__ counts, const int* __restrict__ list,
    float* __restrict__ out) {
  const int e = blockIdx.z, mt = blockIdx.y >> 2, kc = blockIdx.y & 3, nt = blockIdx.x;
  const int cnt = counts[e];
  if (mt * 128 >= cnt) return;
  const int rem = min(128, cnt - mt * 128);
  const int* lst = list + e * TTOK + mt * 128;

  __shared__ __align__(16) unsigned short S[16384];
  unsigned short* As = S;
  unsigned short* Bs = S + 8192;

  const int tid = threadIdx.x;
  const int wave = tid >> 6, lane = tid & 63;
  const int srow = tid >> 2, cell = tid & 3;

  const int p0 = lst[min(srow, rem - 1)];
  const int p1 = lst[min(srow + 64, rem - 1)];
  constexpr int KCH = UDIM / KSPLIT;  // 1024
  const char* ha0 = (const char*)h + ((size_t)p0 * UDIM + kc * KCH) * 2;
  const char* ha1 = (const char*)h + ((size_t)p1 * UDIM + kc * KCH) * 2;
  constexpr int ELT = WBF ? 2 : 4;
  const char* wb0 = (const char*)wsrc + (((size_t)e * DDIM + nt * 128 + srow) * UDIM + kc * KCH) * ELT;
  const char* wb1 = wb0 + (size_t)64 * UDIM * ELT;

  const int ld0 = tid * 16;

  const int wm = wave >> 1, wn = wave & 1;
  const int lane15 = lane & 15, quad = lane >> 4;
  const int aoff = (wm * 64 + lane15) * 32 + quad * 8;
  const int boff = (wn * 64 + lane15) * 32 + quad * 8;

  float4v acc[4][4];
#pragma unroll
  for (int i = 0; i < 4; i++)
#pragma unroll
    for (int j = 0; j < 4; j++) acc[i][j] = (float4v){0.f, 0.f, 0.f, 0.f};

  for (int k0 = 0; k0 < KCH; k0 += 64) {
#pragma unroll
    for (int s = 0; s < 2; s++) {
      const int kb = (k0 + s * 32) * 2 + cell * 16;
      load_lds16(ha0 + kb, (char*)As + s * 8192 + ld0);
      load_lds16(ha1 + kb, (char*)As + s * 8192 + 4096 + ld0);
      if constexpr (WBF) {
        load_lds16(wb0 + kb, (char*)Bs + s * 8192 + ld0);
        load_lds16(wb1 + kb, (char*)Bs + s * 8192 + 4096 + ld0);
      } else {
        const int kf = (k0 + s * 32) * 4 + cell * 32;
        float4v b0 = *(const float4v*)(wb0 + kf), b1 = *(const float4v*)(wb0 + kf + 16);
        float4v b2 = *(const float4v*)(wb1 + kf), b3 = *(const float4v*)(wb1 + kf + 16);
        *(ushort8*)((char*)Bs + s * 8192 + ld0) = pack8(b0, b1);
        *(ushort8*)((char*)Bs + s * 8192 + 4096 + ld0) = pack8(b2, b3);
      }
    }
    __syncthreads();
#pragma unroll
    for (int s = 0; s < 2; s++) {
      short8 af[4], bfr[4];
#pragma unroll
      for (int mi = 0; mi < 4; mi++) af[mi] = *(const short8*)(As + s * 4096 + aoff + mi * 512);
#pragma unroll
      for (int ni = 0; ni < 4; ni++) bfr[ni] = *(const short8*)(Bs + s * 4096 + boff + ni * 512);
#pragma unroll
      for (int mi = 0; mi < 4; mi++)
#pragma unroll
        for (int ni = 0; ni < 4; ni++)
          acc[mi][ni] = __builtin_amdgcn_mfma_f32_16x16x32_bf16(af[mi], bfr[ni], acc[mi][ni], 0, 0, 0);
    }
    __syncthreads();
  }

  const int dcol0 = nt * 128 + wn * 64;
  float bias[4];
#pragma unroll
  for (int ni = 0; ni < 4; ni++)
    bias[ni] = (kc == 0) ? bdn[e * DDIM + dcol0 + ni * 16 + lane15] : 0.0f;
#pragma unroll
  for (int mi = 0; mi < 4; mi++)
#pragma unroll
    for (int r = 0; r < 4; r++) {
      const int mrow = wm * 64 + mi * 16 + quad * 4 + r;
      if (mrow < rem) {
        const int pair = lst[mrow];
        const float w = wpair[pair];
        float* orow = out + (size_t)(pair >> 1) * DDIM;
#pragma unroll
        for (int ni = 0; ni < 4; ni++)
          atomicAdd(&orow[dcol0 + ni * 16 + lane15], w * (acc[mi][ni][r] + bias[ni]));
      }
    }
}

extern "C" void kernel_launch(void* const* d_in, const int* in_sizes, int n_in,
                              void* d_out, int out_size, void* d_ws, size_t ws_size,
                              hipStream_t stream) {
  (void)in_sizes; (void)n_in; (void)out_size;
  const float* x        = (const float*)d_in[0];
  const float* w_router = (const float*)d_in[1];
  const float* w_up     = (const float*)d_in[2];
  const float* b_up     = (const float*)d_in[3];
  const float* w_down   = (const float*)d_in[4];
  const float* b_down   = (const float*)d_in[5];
  float* out = (float*)d_out;

  char* ws = (char*)d_ws;
  size_t off = 0;
  auto take = [&](size_t b) { size_t o = off; off = (off + b + 255) & ~(size_t)255; return o; };
  unsigned short* h = (unsigned short*)(ws + take((size_t)NPAIR * UDIM * 2));   // 64 MiB
  int* counts       = (int*)(ws + take(NEXP * 4));
  int* list         = (int*)(ws + take((size_t)NEXP * TTOK * 4));
  float* wpair      = (float*)(ws + take((size_t)NPAIR * 4));
  size_t xb_off  = take((size_t)TTOK * DDIM * 2);            // 8 MiB
  size_t wub_off = take((size_t)NEXP * UDIM * DDIM * 2);     // 64 MiB
  size_t wdb_off = take((size_t)NEXP * DDIM * UDIM * 2);     // 64 MiB
  const bool full = ws_size >= off;   // ~200 MB

  if (full) {
    unsigned short* xb  = (unsigned short*)(ws + xb_off);
    unsigned short* wub = (unsigned short*)(ws + wub_off);
    unsigned short* wdb = (unsigned short*)(ws + wdb_off);
    prep_kernel<<<4096, 256, 0, stream>>>((const float4v*)x, (const float4v*)w_up,
                                          (const float4v*)w_down, (ushort4v*)xb,
                                          (ushort4v*)wub, (ushort4v*)wdb,
                                          (float4v*)out, counts);
    router_kernel<<<TTOK / 4, 256, 0, stream>>>(x, w_router, counts, list, wpair);
    stage_up_k<true><<<dim3(UDIM / 128, 32, NEXP), 256, 0, stream>>>(xb, wub, b_up, counts, list, h);
    stage_down_k<true><<<dim3(DDIM / 128, 32 * KSPLIT, NEXP), 256, 0, stream>>>(
        h, wdb, b_down, wpair, counts, list, out);
  } else {
    zero_out_counts<<<1024, 256, 0, stream>>>((float4v*)out, counts);
    router_kernel<<<TTOK / 4, 256, 0, stream>>>(x, w_router, counts, list, wpair);
    stage_up_k<false><<<dim3(UDIM / 128, 32, NEXP), 256, 0, stream>>>(x, w_up, b_up, counts, list, h);
    stage_down_k<false><<<dim3(DDIM / 128, 32 * KSPLIT, NEXP), 256, 0, stream>>>(
        h, w_down, b_down, wpair, counts, list, out);
  }
}

// Round 5
// 667.643 us; speedup vs baseline: 1.1660x; 1.0842x over previous
//
#include <hip/hip_runtime.h>
#include <hip/hip_bf16.h>
#include <stdint.h>
#include <math.h>

// Problem constants (B=2,S=2048 -> T=4096 tokens), D=1024, U=4096, E=8, K=2
#define TTOK 4096
#define DDIM 1024
#define UDIM 4096
#define NEXP 8
#define KSPLIT 2            // split-K chunks for stage_down (K=4096 -> 2x2048)
#define KCH   (UDIM / KSPLIT)
#define NPAIR (TTOK * 2)
#define EPAD 72             // epilogue LDS bounce row stride (shorts)

using float4v = __attribute__((ext_vector_type(4))) float;
using short8  = __attribute__((ext_vector_type(8))) short;
using ushort8 = __attribute__((ext_vector_type(8))) unsigned short;

__device__ __forceinline__ unsigned short f2bf(float f) {
  union { float f; unsigned u; } v; v.f = f;
  unsigned r = v.u + 0x7FFFu + ((v.u >> 16) & 1u);  // RNE
  return (unsigned short)(r >> 16);
}
__device__ __forceinline__ float bf2f(unsigned short u) {
  union { unsigned u; float f; } v; v.u = ((unsigned)u) << 16;
  return v.f;
}
__device__ __forceinline__ void load_lds16(const void* g, void* l) {
  __builtin_amdgcn_global_load_lds(
      (const __attribute__((address_space(1))) unsigned int*)g,
      (__attribute__((address_space(3))) unsigned int*)l, 16, 0, 0);
}
// 8 fp32 -> 8 bf16 (RNE), packed; maps to v_cvt_pk_bf16_f32 when available
__device__ __forceinline__ short8 cvt8(const float4v a, const float4v b) {
  union { __hip_bfloat162 h[4]; short8 s; } u;
  u.h[0] = __float22bfloat162_rn(make_float2(a[0], a[1]));
  u.h[1] = __float22bfloat162_rn(make_float2(a[2], a[3]));
  u.h[2] = __float22bfloat162_rn(make_float2(b[0], b[1]));
  u.h[3] = __float22bfloat162_rn(make_float2(b[2], b[3]));
  return u.s;
}
// tanh-form gelu: v * sigmoid(2*0.797885*(v+0.044715 v^3)); NaN-safe at +-inf of exp
__device__ __forceinline__ float gelu_f(float v) {
  float u = v * (0.7978845608f + 0.0356774081f * v * v);
  float ex = __expf(2.0f * u);
  return v * (1.0f - 1.0f / (1.0f + ex));
}

// ---------------- router: logits, top-2, softmax, lists; also emits xb (bf16 x) ----------------
__global__ void router_kernel(const float* __restrict__ x,
                              const float* __restrict__ wr,
                              int* __restrict__ counts, int* __restrict__ list,
                              float* __restrict__ wpair, int* __restrict__ epair,
                              unsigned short* __restrict__ xb) {
  const int t = blockIdx.x * 4 + (threadIdx.x >> 6);
  const int lane = threadIdx.x & 63;
  float acc[NEXP];
#pragma unroll
  for (int e = 0; e < NEXP; e++) acc[e] = 0.0f;
  const float* xr = x + (size_t)t * DDIM;
  unsigned short* xbr = xb + (size_t)t * DDIM;
  for (int d = lane; d < DDIM; d += 64) {
    float xv = xr[d];
    xbr[d] = f2bf(xv);
#pragma unroll
    for (int e = 0; e < NEXP; e++) acc[e] += xv * wr[e * DDIM + d];
  }
#pragma unroll
  for (int e = 0; e < NEXP; e++) {
#pragma unroll
    for (int off = 32; off > 0; off >>= 1) acc[e] += __shfl_xor(acc[e], off, 64);
  }
  if (lane == 0) {
    int e0 = 0; float l0 = acc[0];
    for (int e = 1; e < NEXP; e++) if (acc[e] > l0) { l0 = acc[e]; e0 = e; }
    int e1 = -1; float l1 = -3.4e38f;
    for (int e = 0; e < NEXP; e++) if (e != e0 && acc[e] > l1) { l1 = acc[e]; e1 = e; }
    float s1 = expf(l1 - l0);
    float inv = 1.0f / (1.0f + s1);
    int p0 = atomicAdd(&counts[e0], 1);
    list[e0 * TTOK + p0] = 2 * t;
    wpair[2 * t] = inv;  epair[2 * t] = e0;
    int p1 = atomicAdd(&counts[e1], 1);
    list[e1 * TTOK + p1] = 2 * t + 1;
    wpair[2 * t + 1] = s1 * inv;  epair[2 * t + 1] = e1;
  }
}

// ======== stage A: h[pair,u] = gelu(x . Wup + bup). A: bf16 DMA; B: fp32 DMA + cvt ========
// grid (UDIM/128, 32, NEXP), block 256, BK=32.
__global__ __launch_bounds__(256, 3) void stage_up_k(
    const unsigned short* __restrict__ xb, const float* __restrict__ wu,
    const float* __restrict__ bup, const int* __restrict__ counts,
    const int* __restrict__ list, unsigned short* __restrict__ h) {
  const int e = blockIdx.z, mt = blockIdx.y, nt = blockIdx.x;
  const int cnt = counts[e];
  if (mt * 128 >= cnt) return;
  const int rem = min(128, cnt - mt * 128);
  const int* lst = list + e * TTOK + mt * 128;

  __shared__ __align__(16) char SM[24576];   // A bf16 8K | B fp32 16K; epilogue reuses as bounce
  unsigned short* Sb = (unsigned short*)SM;

  const int tid = threadIdx.x;
  const int wave = tid >> 6, lane = tid & 63;
  const int srow = tid >> 2, cell = tid & 3;          // A dma: 4 thr/row
  const int brow = tid >> 3;                           // B dma: 8 thr/row (fp32 128B rows)
  const int bswz = (tid & 7) ^ (brow & 7);             // XOR source-cell swizzle

  const int tok0 = lst[min(srow, rem - 1)] >> 1;
  const int tok1 = lst[min(srow + 64, rem - 1)] >> 1;
  const unsigned short* a0 = xb + (size_t)tok0 * DDIM + cell * 8;
  const unsigned short* a1 = xb + (size_t)tok1 * DDIM + cell * 8;
  const float* bbase = wu + ((size_t)e * UDIM + nt * 128) * DDIM;
  const float* bsrc[4];
#pragma unroll
  for (int k = 0; k < 4; k++) bsrc[k] = bbase + (size_t)(brow + k * 32) * DDIM + bswz * 4;

  const int wm = wave >> 1, wn = wave & 1;
  const int lane15 = lane & 15, quad = lane >> 4;
  const int abyte = (wm * 64 + lane15) * 64 + quad * 16;            // A frag base (bytes)
  const int p0 = (2 * quad) ^ (lane & 7);                           // swizzled B cell
  const int bbyte = 8192 + (wn * 64 + lane15) * 128;                // B frag row base (bytes)

  float4v acc[4][4];
#pragma unroll
  for (int i = 0; i < 4; i++)
#pragma unroll
    for (int j = 0; j < 4; j++) acc[i][j] = (float4v){0.f, 0.f, 0.f, 0.f};

  for (int k0 = 0; k0 < DDIM; k0 += 32) {
    load_lds16(a0 + k0, SM + tid * 16);
    load_lds16(a1 + k0, SM + 4096 + tid * 16);
#pragma unroll
    for (int k = 0; k < 4; k++) load_lds16(bsrc[k] + k0, SM + 8192 + k * 4096 + tid * 16);
    __syncthreads();
    short8 af[4], bfr[4];
#pragma unroll
    for (int mi = 0; mi < 4; mi++) af[mi] = *(const short8*)(SM + abyte + mi * 1024);
#pragma unroll
    for (int ni = 0; ni < 4; ni++) {
      const char* rb = SM + bbyte + ni * 2048;
      float4v f0 = *(const float4v*)(rb + p0 * 16);
      float4v f1 = *(const float4v*)(rb + (p0 ^ 1) * 16);
      bfr[ni] = cvt8(f0, f1);
    }
#pragma unroll
    for (int mi = 0; mi < 4; mi++)
#pragma unroll
      for (int ni = 0; ni < 4; ni++)
        acc[mi][ni] = __builtin_amdgcn_mfma_f32_16x16x32_bf16(af[mi], bfr[ni], acc[mi][ni], 0, 0, 0);
    __syncthreads();
  }

  // epilogue: +bias, fast gelu -> bf16, LDS bounce, coalesced 16B stores
  const int ucol0 = nt * 128 + wn * 64;
  float bias[4];
#pragma unroll
  for (int ni = 0; ni < 4; ni++) bias[ni] = bup[e * UDIM + ucol0 + ni * 16 + lane15];
  const int row = tid >> 1, seg = tid & 1;
  const int opair = (row < rem) ? lst[row] : -1;
#pragma unroll
  for (int hh = 0; hh < 2; hh++) {
    if (wn == hh) {
#pragma unroll
      for (int mi = 0; mi < 4; mi++)
#pragma unroll
        for (int r = 0; r < 4; r++) {
          const int rl = wm * 64 + mi * 16 + quad * 4 + r;
#pragma unroll
          for (int ni = 0; ni < 4; ni++)
            Sb[rl * EPAD + ni * 16 + lane15] = f2bf(gelu_f(acc[mi][ni][r] + bias[ni]));
        }
    }
    __syncthreads();
    if (opair >= 0) {
      unsigned short* dst = h + (size_t)opair * UDIM + nt * 128 + hh * 64 + seg * 32;
      const unsigned short* src = Sb + row * EPAD + seg * 32;
#pragma unroll
      for (int c = 0; c < 4; c++) *(ushort8*)(dst + c * 8) = *(const ushort8*)(src + c * 8);
    }
    __syncthreads();
  }
}

// ======== stage B: partial[kc][pair] = h . Wdown (no bias/w). A: h bf16 DMA; B: fp32 DMA + cvt ========
// grid (DDIM/128, 32*KSPLIT, NEXP), block 256, BK=32. PARTM=false: atomic fallback.
template <bool PARTM>
__global__ __launch_bounds__(256, 3) void stage_down_k(
    const unsigned short* __restrict__ h, const float* __restrict__ wd,
    const float* __restrict__ bdn, const float* __restrict__ wpair,
    const int* __restrict__ counts, const int* __restrict__ list,
    unsigned short* __restrict__ part, float* __restrict__ out) {
  const int e = blockIdx.z, mt = blockIdx.y >> 1, kc = blockIdx.y & 1, nt = blockIdx.x;
  const int cnt = counts[e];
  if (mt * 128 >= cnt) return;
  const int rem = min(128, cnt - mt * 128);
  const int* lst = list + e * TTOK + mt * 128;

  __shared__ __align__(16) char SM[24576];
  unsigned short* Sb = (unsigned short*)SM;

  const int tid = threadIdx.x;
  const int wave = tid >> 6, lane = tid & 63;
  const int srow = tid >> 2, cell = tid & 3;
  const int brow = tid >> 3;
  const int bswz = (tid & 7) ^ (brow & 7);

  const int pr0 = lst[min(srow, rem - 1)];
  const int pr1 = lst[min(srow + 64, rem - 1)];
  const unsigned short* a0 = h + (size_t)pr0 * UDIM + kc * KCH + cell * 8;
  const unsigned short* a1 = h + (size_t)pr1 * UDIM + kc * KCH + cell * 8;
  const float* bbase = wd + ((size_t)e * DDIM + nt * 128) * UDIM + kc * KCH;
  const float* bsrc[4];
#pragma unroll
  for (int k = 0; k < 4; k++) bsrc[k] = bbase + (size_t)(brow + k * 32) * UDIM + bswz * 4;

  const int wm = wave >> 1, wn = wave & 1;
  const int lane15 = lane & 15, quad = lane >> 4;
  const int abyte = (wm * 64 + lane15) * 64 + quad * 16;
  const int p0 = (2 * quad) ^ (lane & 7);
  const int bbyte = 8192 + (wn * 64 + lane15) * 128;

  float4v acc[4][4];
#pragma unroll
  for (int i = 0; i < 4; i++)
#pragma unroll
    for (int j = 0; j < 4; j++) acc[i][j] = (float4v){0.f, 0.f, 0.f, 0.f};

  for (int k0 = 0; k0 < KCH; k0 += 32) {
    load_lds16(a0 + k0, SM + tid * 16);
    load_lds16(a1 + k0, SM + 4096 + tid * 16);
#pragma unroll
    for (int k = 0; k < 4; k++) load_lds16(bsrc[k] + k0, SM + 8192 + k * 4096 + tid * 16);
    __syncthreads();
    short8 af[4], bfr[4];
#pragma unroll
    for (int mi = 0; mi < 4; mi++) af[mi] = *(const short8*)(SM + abyte + mi * 1024);
#pragma unroll
    for (int ni = 0; ni < 4; ni++) {
      const char* rb = SM + bbyte + ni * 2048;
      float4v f0 = *(const float4v*)(rb + p0 * 16);
      float4v f1 = *(const float4v*)(rb + (p0 ^ 1) * 16);
      bfr[ni] = cvt8(f0, f1);
    }
#pragma unroll
    for (int mi = 0; mi < 4; mi++)
#pragma unroll
      for (int ni = 0; ni < 4; ni++)
        acc[mi][ni] = __builtin_amdgcn_mfma_f32_16x16x32_bf16(af[mi], bfr[ni], acc[mi][ni], 0, 0, 0);
    __syncthreads();
  }

  const int dcol0 = nt * 128 + wn * 64;
  if constexpr (PARTM) {
    const int row = tid >> 1, seg = tid & 1;
    const int opair = (row < rem) ? lst[row] : -1;
#pragma unroll
    for (int hh = 0; hh < 2; hh++) {
      if (wn == hh) {
#pragma unroll
        for (int mi = 0; mi < 4; mi++)
#pragma unroll
          for (int r = 0; r < 4; r++) {
            const int rl = wm * 64 + mi * 16 + quad * 4 + r;
#pragma unroll
            for (int ni = 0; ni < 4; ni++)
              Sb[rl * EPAD + ni * 16 + lane15] = f2bf(acc[mi][ni][r]);
          }
      }
      __syncthreads();
      if (opair >= 0) {
        unsigned short* dst = part + ((size_t)kc * NPAIR + opair) * DDIM + nt * 128 + hh * 64 + seg * 32;
        const unsigned short* src = Sb + row * EPAD + seg * 32;
#pragma unroll
        for (int c = 0; c < 4; c++) *(ushort8*)(dst + c * 8) = *(const ushort8*)(src + c * 8);
      }
      __syncthreads();
    }
  } else {
    float bias[4];
#pragma unroll
    for (int ni = 0; ni < 4; ni++)
      bias[ni] = (kc == 0) ? bdn[e * DDIM + dcol0 + ni * 16 + lane15] : 0.0f;
#pragma unroll
    for (int mi = 0; mi < 4; mi++)
#pragma unroll
      for (int r = 0; r < 4; r++) {
        const int mrow = wm * 64 + mi * 16 + quad * 4 + r;
        if (mrow < rem) {
          const int pair = lst[mrow];
          const float w = wpair[pair];
          float* orow = out + (size_t)(pair >> 1) * DDIM;
#pragma unroll
          for (int ni = 0; ni < 4; ni++)
            atomicAdd(&orow[dcol0 + ni * 16 + lane15], w * (acc[mi][ni][r] + bias[ni]));
        }
      }
  }
}

// ---------------- combine: out[t,d] = sum_j w_j * (bdn[e_j,d] + sum_kc part[kc,2t+j,d]) ----------------
__global__ void combine_kernel(const unsigned short* __restrict__ part,
                               const float* __restrict__ bdn,
                               const float* __restrict__ wpair,
                               const int* __restrict__ epair,
                               float* __restrict__ out) {
  const int idx = blockIdx.x * 256 + threadIdx.x;
  const int t = idx >> 7, c8 = (idx & 127) * 8;
  const size_t kstride = (size_t)NPAIR * DDIM;
  const unsigned short* pa = part + (size_t)(2 * t) * DDIM + c8;
  float s0[8], s1[8];
#pragma unroll
  for (int j = 0; j < 8; j++) { s0[j] = 0.f; s1[j] = 0.f; }
#pragma unroll
  for (int kc = 0; kc < KSPLIT; kc++) {
    ushort8 a = *(const ushort8*)(pa + kc * kstride);
    ushort8 b = *(const ushort8*)(pa + kc * kstride + DDIM);
#pragma unroll
    for (int j = 0; j < 8; j++) { s0[j] += bf2f(a[j]); s1[j] += bf2f(b[j]); }
  }
  const float w0 = wpair[2 * t], w1 = wpair[2 * t + 1];
  const int e0 = epair[2 * t], e1 = epair[2 * t + 1];
  const float* b0 = bdn + e0 * DDIM + c8;
  const float* b1 = bdn + e1 * DDIM + c8;
  float4v o[2];
#pragma unroll
  for (int half = 0; half < 2; half++)
#pragma unroll
    for (int j = 0; j < 4; j++) {
      const int jj = half * 4 + j;
      o[half][j] = w0 * (s0[jj] + b0[jj]) + w1 * (s1[jj] + b1[jj]);
    }
  float4v* dst = (float4v*)(out + (size_t)t * DDIM + c8);
  dst[0] = o[0]; dst[1] = o[1];
}

__global__ void zero_out_k(float4v* __restrict__ out) {
  const int tid = blockIdx.x * blockDim.x + threadIdx.x;
  const int O4 = TTOK * DDIM / 4;
  const int stride = gridDim.x * blockDim.x;
  for (int i = tid; i < O4; i += stride) out[i] = (float4v){0.f, 0.f, 0.f, 0.f};
}

extern "C" void kernel_launch(void* const* d_in, const int* in_sizes, int n_in,
                              void* d_out, int out_size, void* d_ws, size_t ws_size,
                              hipStream_t stream) {
  (void)in_sizes; (void)n_in; (void)out_size;
  const float* x        = (const float*)d_in[0];
  const float* w_router = (const float*)d_in[1];
  const float* w_up     = (const float*)d_in[2];
  const float* b_up     = (const float*)d_in[3];
  const float* w_down   = (const float*)d_in[4];
  const float* b_down   = (const float*)d_in[5];
  float* out = (float*)d_out;

  char* ws = (char*)d_ws;
  size_t off = 0;
  auto take = [&](size_t b) { size_t o = off; off = (off + b + 255) & ~(size_t)255; return o; };
  unsigned short* h  = (unsigned short*)(ws + take((size_t)NPAIR * UDIM * 2));   // 64 MiB
  unsigned short* xb = (unsigned short*)(ws + take((size_t)TTOK * DDIM * 2));    // 8 MiB
  int* counts        = (int*)(ws + take(NEXP * 4));
  int* list          = (int*)(ws + take((size_t)NEXP * TTOK * 4));
  float* wpair       = (float*)(ws + take((size_t)NPAIR * 4));
  int* epair         = (int*)(ws + take((size_t)NPAIR * 4));
  size_t part_off    = take((size_t)KSPLIT * NPAIR * DDIM * 2);                  // 32 MiB
  const bool partmode = ws_size >= off;

  hipMemsetAsync(counts, 0, NEXP * 4, stream);
  router_kernel<<<TTOK / 4, 256, 0, stream>>>(x, w_router, counts, list, wpair, epair, xb);
  stage_up_k<<<dim3(UDIM / 128, 32, NEXP), 256, 0, stream>>>(xb, w_up, b_up, counts, list, h);

  if (partmode) {
    unsigned short* part = (unsigned short*)(ws + part_off);
    stage_down_k<true><<<dim3(DDIM / 128, 32 * KSPLIT, NEXP), 256, 0, stream>>>(
        h, w_down, b_down, wpair, counts, list, part, out);
    combine_kernel<<<TTOK * DDIM / 8 / 256, 256, 0, stream>>>(part, b_down, wpair, epair, out);
  } else {
    zero_out_k<<<1024, 256, 0, stream>>>((float4v*)out);
    stage_down_k<false><<<dim3(DDIM / 128, 32 * KSPLIT, NEXP), 256, 0, stream>>>(
        h, w_down, b_down, wpair, counts, list, (unsigned short*)nullptr, out);
  }
}